// Round 1
// baseline (830.157 us; speedup 1.0000x reference)
//
#include <hip/hip_runtime.h>

// FullyConnectedTensorProduct: irreps 64x(0e+1o+2e) x same -> same, N=4096.
// out[z, OFF[io] + w*(2lo+1) + k] = (1/24) * sum_p sum_{u,v,i,j} W[p][u][v][w]*CG_p[i,j,k]*x1[z,u,i]*x2[z,v,j]
//
// Strategy: bf16 MFMA GEMM over K=uv (4096) per (path, kout); A = T computed on the fly
// in registers in fragment layout (no LDS, no barriers); B = pre-transposed bf16 W.

typedef unsigned short u16;
typedef __attribute__((ext_vector_type(8))) short bf16x8;   // 8 bf16 in 4 VGPRs
typedef __attribute__((ext_vector_type(4))) float f32x4;

#define NZ 4096
#define ROWE 832   // padded bf16 elems per z-row: seg0 64*1 + seg1 64*4 + seg2 64*8

__device__ __forceinline__ u16 f2bf(float x) {               // RNE f32->bf16
    unsigned u = __float_as_uint(x);
    return (u16)((u + 0x7FFFu + ((u >> 16) & 1u)) >> 16);
}
__device__ __forceinline__ float bf2f(u16 b) {
    return __uint_as_float(((unsigned)b) << 16);
}

// ---------------- Clebsch-Gordan tables (real basis, reference phase conventions) ----
// Derived from Racah formula + q(l) basis change with (-i)^l phases; per-k norms == 1.
struct CGE { int i, j, k; float c; };
template<int P> struct CGT;
// p0 (0,0,0)
template<> struct CGT<0> { static constexpr int n=1; static constexpr CGE e[1]={{0,0,0,1.0f}}; };
// p1 (1,1,0): delta/sqrt(3)
template<> struct CGT<1> { static constexpr int n=3; static constexpr CGE e[3]={
    {0,0,0,0.5773502691896258f},{1,1,0,0.5773502691896258f},{2,2,0,0.5773502691896258f}}; };
// p2 (2,2,0): delta/sqrt(5)
template<> struct CGT<2> { static constexpr int n=5; static constexpr CGE e[5]={
    {0,0,0,0.4472135954999579f},{1,1,0,0.4472135954999579f},{2,2,0,0.4472135954999579f},
    {3,3,0,0.4472135954999579f},{4,4,0,0.4472135954999579f}}; };
// p3 (0,1,1): delta_bc
template<> struct CGT<3> { static constexpr int n=3; static constexpr CGE e[3]={
    {0,0,0,1.0f},{0,1,1,1.0f},{0,2,2,1.0f}}; };
// p4 (1,0,1): delta_ac
template<> struct CGT<4> { static constexpr int n=3; static constexpr CGE e[3]={
    {0,0,0,1.0f},{1,0,1,1.0f},{2,0,2,1.0f}}; };
// p5 (1,2,1)
template<> struct CGT<5> { static constexpr int n=11; static constexpr CGE e[11]={
    {0,2,0,-0.31622776601683794f},{1,1,0,0.5477225575051661f},{0,4,0,-0.5477225575051661f},{2,0,0,0.5477225575051661f},
    {0,1,1,0.5477225575051661f},{2,3,1,0.5477225575051661f},{1,2,1,0.6324555320336759f},
    {2,2,2,-0.31622776601683794f},{1,3,2,0.5477225575051661f},{0,0,2,0.5477225575051661f},{2,4,2,0.5477225575051661f}}; };
// p6 (2,1,1): transpose of p5 in (i,j)
template<> struct CGT<6> { static constexpr int n=11; static constexpr CGE e[11]={
    {2,0,0,-0.31622776601683794f},{1,1,0,0.5477225575051661f},{4,0,0,-0.5477225575051661f},{0,2,0,0.5477225575051661f},
    {1,0,1,0.5477225575051661f},{3,2,1,0.5477225575051661f},{2,1,1,0.6324555320336759f},
    {2,2,2,-0.31622776601683794f},{3,1,2,0.5477225575051661f},{0,0,2,0.5477225575051661f},{4,2,2,0.5477225575051661f}}; };
// p7 (0,2,2): delta_bc
template<> struct CGT<7> { static constexpr int n=5; static constexpr CGE e[5]={
    {0,0,0,1.0f},{0,1,1,1.0f},{0,2,2,1.0f},{0,3,3,1.0f},{0,4,4,1.0f}}; };
// p8 (1,1,2)
template<> struct CGT<8> { static constexpr int n=11; static constexpr CGE e[11]={
    {0,2,0,0.7071067811865476f},{2,0,0,0.7071067811865476f},
    {0,1,1,0.7071067811865476f},{1,0,1,0.7071067811865476f},
    {0,0,2,-0.4082482904638630f},{1,1,2,0.8164965809277260f},{2,2,2,-0.4082482904638630f},
    {1,2,3,0.7071067811865476f},{2,1,3,0.7071067811865476f},
    {0,0,4,-0.7071067811865476f},{2,2,4,0.7071067811865476f}}; };
// p9 (2,0,2): delta_ac
template<> struct CGT<9> { static constexpr int n=5; static constexpr CGE e[5]={
    {0,0,0,1.0f},{1,0,1,1.0f},{2,0,2,1.0f},{3,0,3,1.0f},{4,0,4,1.0f}}; };
// p10 (2,2,2)
template<> struct CGT<10> { static constexpr int n=25; static constexpr CGE e[25]={
    {0,2,0,-0.5345224838248488f},{2,0,0,-0.5345224838248488f},{1,3,0,0.4629100498862757f},{3,1,0,0.4629100498862757f},
    {0,3,1,0.4629100498862757f},{3,0,1,0.4629100498862757f},{1,4,1,-0.4629100498862757f},{4,1,1,-0.4629100498862757f},
    {1,2,1,0.2672612419124244f},{2,1,1,0.2672612419124244f},
    {0,0,2,-0.5345224838248488f},{1,1,2,0.2672612419124244f},{2,2,2,0.5345224838248488f},{3,3,2,0.2672612419124244f},{4,4,2,-0.5345224838248488f},
    {0,1,3,0.4629100498862757f},{1,0,3,0.4629100498862757f},{3,4,3,0.4629100498862757f},{4,3,3,0.4629100498862757f},
    {2,3,3,0.2672612419124244f},{3,2,3,0.2672612419124244f},
    {1,1,4,-0.4629100498862757f},{3,3,4,0.4629100498862757f},{2,4,4,-0.5345224838248488f},{4,2,4,-0.5345224838248488f}}; };

// ---------------- padded x layout helpers ----------------
template<int SEG>
__device__ __forceinline__ int soff(int m) {
    if constexpr (SEG == 0) return m;              // width 1
    else if constexpr (SEG == 1) return 64 + 4*m;  // width 3 padded to 4
    else return 320 + 8*m;                         // width 5 padded to 8
}
template<int L>
__device__ __forceinline__ void load_xvec(const u16* p, float* o) {
    if constexpr (L == 0) {
        o[0] = bf2f(p[0]);
    } else if constexpr (L == 1) {
        uint2 r = *reinterpret_cast<const uint2*>(p);
        o[0] = bf2f((u16)(r.x & 0xffff)); o[1] = bf2f((u16)(r.x >> 16)); o[2] = bf2f((u16)(r.y & 0xffff));
    } else {
        uint4 r = *reinterpret_cast<const uint4*>(p);
        o[0] = bf2f((u16)(r.x & 0xffff)); o[1] = bf2f((u16)(r.x >> 16));
        o[2] = bf2f((u16)(r.y & 0xffff)); o[3] = bf2f((u16)(r.y >> 16));
        o[4] = bf2f((u16)(r.z & 0xffff));
    }
}

// ---------------- one path: accumulate MFMA GEMM over K=uv for a fixed kout ----------
template<int PID, int SEG1, int SEG2, int KOUT>
__device__ __forceinline__ void run_path(const u16* __restrict__ x1r, const u16* __restrict__ x2r,
                                         const u16* __restrict__ Wtb, f32x4* acc, int lane) {
    constexpr int D1 = 2*SEG1 + 1, D2 = 2*SEG2 + 1;
    const int kb = lane >> 4;    // k-block 0..3 within MFMA K=32
    const int nl = lane & 15;
    // register-cache x2 for this lane's 16 possible v values (both K-halves), whole K-loop
    float b2[16][D2];
    #pragma unroll
    for (int h = 0; h < 2; ++h) {
        #pragma unroll
        for (int e = 0; e < 8; ++e) {
            const int v = h*32 + kb*8 + e;
            load_xvec<SEG2>(x2r + soff<SEG2>(v), b2[h*8 + e]);
        }
    }
    const u16* wp = Wtb + PID*(64*4096) + nl*4096;
    for (int u = 0; u < 64; ++u) {
        float a1[D1];
        load_xvec<SEG1>(x1r + soff<SEG1>(u), a1);
        // pre-multiply CG coeff * x1[i] (shared over the 16 K-elements)
        float pre[CGT<PID>::n];
        #pragma unroll
        for (int t = 0; t < CGT<PID>::n; ++t)
            pre[t] = (CGT<PID>::e[t].k == KOUT) ? CGT<PID>::e[t].c * a1[CGT<PID>::e[t].i] : 0.0f;
        #pragma unroll
        for (int h = 0; h < 2; ++h) {
            bf16x8 af;
            #pragma unroll
            for (int e = 0; e < 8; ++e) {
                float s = 0.0f;
                #pragma unroll
                for (int t = 0; t < CGT<PID>::n; ++t)
                    if (CGT<PID>::e[t].k == KOUT)
                        s += pre[t] * b2[h*8 + e][CGT<PID>::e[t].j];
                af[e] = (short)f2bf(s);
            }
            const int kidx = u*64 + h*32 + kb*8;
            #pragma unroll
            for (int nf = 0; nf < 4; ++nf) {
                bf16x8 bfrag = *reinterpret_cast<const bf16x8*>(wp + nf*16*4096 + kidx);
                acc[nf] = __builtin_amdgcn_mfma_f32_16x16x32_bf16(af, bfrag, acc[nf], 0, 0, 0);
            }
        }
    }
}

// ---------------- one unit = (io, kout): 3-4 paths into shared accumulators ----------
template<int IO, int KOUT>
__device__ __forceinline__ void run_unit(const u16* __restrict__ XB1, const u16* __restrict__ XB2,
                                         const u16* __restrict__ Wtb, float* __restrict__ out, int ztile) {
    const int lane = threadIdx.x & 63;
    const int wave = threadIdx.x >> 6;
    const int zin = ztile*64 + wave*16 + (lane & 15);   // A-fragment row
    const u16* x1r = XB1 + zin*ROWE;
    const u16* x2r = XB2 + zin*ROWE;
    f32x4 acc[4];
    #pragma unroll
    for (int nf = 0; nf < 4; ++nf) acc[nf] = (f32x4){0.f, 0.f, 0.f, 0.f};

    if constexpr (IO == 0) {
        run_path<0,0,0,KOUT>(x1r, x2r, Wtb, acc, lane);
        run_path<1,1,1,KOUT>(x1r, x2r, Wtb, acc, lane);
        run_path<2,2,2,KOUT>(x1r, x2r, Wtb, acc, lane);
    } else if constexpr (IO == 1) {
        run_path<3,0,1,KOUT>(x1r, x2r, Wtb, acc, lane);
        run_path<4,1,0,KOUT>(x1r, x2r, Wtb, acc, lane);
        run_path<5,1,2,KOUT>(x1r, x2r, Wtb, acc, lane);
        run_path<6,2,1,KOUT>(x1r, x2r, Wtb, acc, lane);
    } else {
        run_path<7,0,2,KOUT>(x1r, x2r, Wtb, acc, lane);
        run_path<8,1,1,KOUT>(x1r, x2r, Wtb, acc, lane);
        run_path<9,2,0,KOUT>(x1r, x2r, Wtb, acc, lane);
        run_path<10,2,2,KOUT>(x1r, x2r, Wtb, acc, lane);
    }
    // epilogue: C/D layout col=lane&15 (w), row=(lane>>4)*4+reg (z)
    constexpr int KO   = 2*IO + 1;
    constexpr int OFFI = (IO == 0) ? 0 : (IO == 1 ? 64 : 256);
    const int zoutb = ztile*64 + wave*16 + (lane >> 4)*4;
    const int nl = lane & 15;
    #pragma unroll
    for (int nf = 0; nf < 4; ++nf) {
        const int wcol = nf*16 + nl;
        #pragma unroll
        for (int r = 0; r < 4; ++r)
            out[(zoutb + r)*576 + OFFI + wcol*KO + KOUT] = acc[nf][r] * 0.041666666666666664f;
    }
}

__global__ __launch_bounds__(256) void tp_main(const u16* __restrict__ XB1, const u16* __restrict__ XB2,
                                               const u16* __restrict__ Wtb, float* __restrict__ out) {
    const int unit  = blockIdx.x % 9;
    const int ztile = blockIdx.x / 9;
    switch (unit) {
        case 0: run_unit<0,0>(XB1, XB2, Wtb, out, ztile); break;
        case 1: run_unit<1,0>(XB1, XB2, Wtb, out, ztile); break;
        case 2: run_unit<1,1>(XB1, XB2, Wtb, out, ztile); break;
        case 3: run_unit<1,2>(XB1, XB2, Wtb, out, ztile); break;
        case 4: run_unit<2,0>(XB1, XB2, Wtb, out, ztile); break;
        case 5: run_unit<2,1>(XB1, XB2, Wtb, out, ztile); break;
        case 6: run_unit<2,2>(XB1, XB2, Wtb, out, ztile); break;
        case 7: run_unit<2,3>(XB1, XB2, Wtb, out, ztile); break;
        default: run_unit<2,4>(XB1, XB2, Wtb, out, ztile); break;
    }
}

// ---------------- prep kernels ----------------
// x -> padded bf16 rows [z][ROWE]
__global__ void prep_x(const float* __restrict__ x1, const float* __restrict__ x2,
                       u16* __restrict__ XB1, u16* __restrict__ XB2) {
    int g = blockIdx.x * 256 + threadIdx.x;
    const int PER = NZ * 192;
    if (g >= 2*PER) return;
    const float* src; u16* dst;
    if (g < PER) { src = x1; dst = XB1; } else { src = x2; dst = XB2; g -= PER; }
    const int zz = g / 192, s = g - zz*192, seg = s >> 6, m = s & 63;
    const float* sp = src + zz*576;
    u16* dp = dst + zz*ROWE;
    if (seg == 0) {
        dp[m] = f2bf(sp[m]);
    } else if (seg == 1) {
        u16 t0 = f2bf(sp[64 + m*3 + 0]);
        u16 t1 = f2bf(sp[64 + m*3 + 1]);
        u16 t2 = f2bf(sp[64 + m*3 + 2]);
        uint2 pk; pk.x = (unsigned)t0 | ((unsigned)t1 << 16); pk.y = (unsigned)t2;
        *reinterpret_cast<uint2*>(dp + 64 + m*4) = pk;
    } else {
        u16 t[5];
        #pragma unroll
        for (int c = 0; c < 5; ++c) t[c] = f2bf(sp[256 + m*5 + c]);
        uint4 pk;
        pk.x = (unsigned)t[0] | ((unsigned)t[1] << 16);
        pk.y = (unsigned)t[2] | ((unsigned)t[3] << 16);
        pk.z = (unsigned)t[4];
        pk.w = 0u;
        *reinterpret_cast<uint4*>(dp + 320 + m*8) = pk;
    }
}

// W[p][u][v][w] f32 -> Wt[p][w][u*64+v] bf16 (B^T, K-major)
__global__ void prep_w(const float* __restrict__ W, u16* __restrict__ Wtb) {
    const int b = blockIdx.x;            // 0..703 : (p,u)
    const int p = b >> 6, u = b & 63;
    const int t = threadIdx.x;
    const int w = t & 63, vg = t >> 6;   // 64 w x 4 v-groups
    const float* src = W + (((p*64 + u)*64) * 64) + w;     // + v*64
    u16* dst = Wtb + (p*64 + w)*4096 + u*64;
    #pragma unroll
    for (int q = 0; q < 16; ++q) {
        const int v = vg*16 + q;
        dst[v] = f2bf(src[v*64]);
    }
}

extern "C" void kernel_launch(void* const* d_in, const int* in_sizes, int n_in,
                              void* d_out, int out_size, void* d_ws, size_t ws_size,
                              hipStream_t stream) {
    const float* x1 = (const float*)d_in[0];
    const float* x2 = (const float*)d_in[1];
    const float* W  = (const float*)d_in[2];
    float* out = (float*)d_out;

    u16* XB1 = (u16*)d_ws;                 // 4096*832*2  = 6.8 MB
    u16* XB2 = XB1 + NZ*ROWE;              // 6.8 MB
    u16* Wtb = XB2 + NZ*ROWE;              // 11*64*4096*2 = 5.8 MB
    if (ws_size < (size_t)(2*NZ*ROWE + 11*64*4096) * sizeof(u16)) return;

    hipLaunchKernelGGL(prep_x, dim3((2*NZ*192 + 255)/256), dim3(256), 0, stream, x1, x2, XB1, XB2);
    hipLaunchKernelGGL(prep_w, dim3(11*64), dim3(256), 0, stream, W, Wtb);
    hipLaunchKernelGGL(tp_main, dim3(64*9), dim3(256), 0, stream, XB1, XB2, Wtb, out);
}

// Round 2
// 310.042 us; speedup vs baseline: 2.6776x; 2.6776x over previous
//
#include <hip/hip_runtime.h>

// FullyConnectedTensorProduct: irreps 64x(0e+1o+2e) x same -> same, N=4096.
// out[z, OFF[io] + w*(2lo+1) + k] = (1/24) * sum_p sum_{u,v,i,j} W[p][u][v][w]*CG_p[i,j,k]*x1[z,u,i]*x2[z,v,j]
//
// R2: bf16 MFMA GEMM over K=uv per (path,kout); A = T computed on the fly in registers;
// B = Wt staged global->LDS via global_load_lds (width 16), double-buffered, chunk = 4 u.
// Bank-conflict XOR swizzle is baked into the Wt workspace layout (prep_w pre-swizzles,
// global_load_lds writes linearly, ds_read applies the swizzle).

typedef unsigned short u16;
typedef __attribute__((ext_vector_type(8))) short bf16x8;   // 8 bf16 in 4 VGPRs
typedef __attribute__((ext_vector_type(4))) float f32x4;

#define NZ 4096
#define ROWE 832   // padded bf16 elems per z-row: seg0 64*1 + seg1 64*4 + seg2 64*8

__device__ __forceinline__ u16 f2bf(float x) {               // RNE f32->bf16
    unsigned u = __float_as_uint(x);
    return (u16)((u + 0x7FFFu + ((u >> 16) & 1u)) >> 16);
}
__device__ __forceinline__ float bf2f(u16 b) {
    return __uint_as_float(((unsigned)b) << 16);
}

// ---------------- Clebsch-Gordan tables (real basis, reference phase conventions) ----
struct CGE { int i, j, k; float c; };
template<int P> struct CGT;
template<> struct CGT<0> { static constexpr int n=1; static constexpr CGE e[1]={{0,0,0,1.0f}}; };
template<> struct CGT<1> { static constexpr int n=3; static constexpr CGE e[3]={
    {0,0,0,0.5773502691896258f},{1,1,0,0.5773502691896258f},{2,2,0,0.5773502691896258f}}; };
template<> struct CGT<2> { static constexpr int n=5; static constexpr CGE e[5]={
    {0,0,0,0.4472135954999579f},{1,1,0,0.4472135954999579f},{2,2,0,0.4472135954999579f},
    {3,3,0,0.4472135954999579f},{4,4,0,0.4472135954999579f}}; };
template<> struct CGT<3> { static constexpr int n=3; static constexpr CGE e[3]={
    {0,0,0,1.0f},{0,1,1,1.0f},{0,2,2,1.0f}}; };
template<> struct CGT<4> { static constexpr int n=3; static constexpr CGE e[3]={
    {0,0,0,1.0f},{1,0,1,1.0f},{2,0,2,1.0f}}; };
template<> struct CGT<5> { static constexpr int n=11; static constexpr CGE e[11]={
    {0,2,0,-0.31622776601683794f},{1,1,0,0.5477225575051661f},{0,4,0,-0.5477225575051661f},{2,0,0,0.5477225575051661f},
    {0,1,1,0.5477225575051661f},{2,3,1,0.5477225575051661f},{1,2,1,0.6324555320336759f},
    {2,2,2,-0.31622776601683794f},{1,3,2,0.5477225575051661f},{0,0,2,0.5477225575051661f},{2,4,2,0.5477225575051661f}}; };
template<> struct CGT<6> { static constexpr int n=11; static constexpr CGE e[11]={
    {2,0,0,-0.31622776601683794f},{1,1,0,0.5477225575051661f},{4,0,0,-0.5477225575051661f},{0,2,0,0.5477225575051661f},
    {1,0,1,0.5477225575051661f},{3,2,1,0.5477225575051661f},{2,1,1,0.6324555320336759f},
    {2,2,2,-0.31622776601683794f},{3,1,2,0.5477225575051661f},{0,0,2,0.5477225575051661f},{4,2,2,0.5477225575051661f}}; };
template<> struct CGT<7> { static constexpr int n=5; static constexpr CGE e[5]={
    {0,0,0,1.0f},{0,1,1,1.0f},{0,2,2,1.0f},{0,3,3,1.0f},{0,4,4,1.0f}}; };
template<> struct CGT<8> { static constexpr int n=11; static constexpr CGE e[11]={
    {0,2,0,0.7071067811865476f},{2,0,0,0.7071067811865476f},
    {0,1,1,0.7071067811865476f},{1,0,1,0.7071067811865476f},
    {0,0,2,-0.4082482904638630f},{1,1,2,0.8164965809277260f},{2,2,2,-0.4082482904638630f},
    {1,2,3,0.7071067811865476f},{2,1,3,0.7071067811865476f},
    {0,0,4,-0.7071067811865476f},{2,2,4,0.7071067811865476f}}; };
template<> struct CGT<9> { static constexpr int n=5; static constexpr CGE e[5]={
    {0,0,0,1.0f},{1,0,1,1.0f},{2,0,2,1.0f},{3,0,3,1.0f},{4,0,4,1.0f}}; };
template<> struct CGT<10> { static constexpr int n=25; static constexpr CGE e[25]={
    {0,2,0,-0.5345224838248488f},{2,0,0,-0.5345224838248488f},{1,3,0,0.4629100498862757f},{3,1,0,0.4629100498862757f},
    {0,3,1,0.4629100498862757f},{3,0,1,0.4629100498862757f},{1,4,1,-0.4629100498862757f},{4,1,1,-0.4629100498862757f},
    {1,2,1,0.2672612419124244f},{2,1,1,0.2672612419124244f},
    {0,0,2,-0.5345224838248488f},{1,1,2,0.2672612419124244f},{2,2,2,0.5345224838248488f},{3,3,2,0.2672612419124244f},{4,4,2,-0.5345224838248488f},
    {0,1,3,0.4629100498862757f},{1,0,3,0.4629100498862757f},{3,4,3,0.4629100498862757f},{4,3,3,0.4629100498862757f},
    {2,3,3,0.2672612419124244f},{3,2,3,0.2672612419124244f},
    {1,1,4,-0.4629100498862757f},{3,3,4,0.4629100498862757f},{2,4,4,-0.5345224838248488f},{4,2,4,-0.5345224838248488f}}; };

// ---------------- padded x layout helpers ----------------
template<int SEG>
__device__ __forceinline__ int soff(int m) {
    if constexpr (SEG == 0) return m;              // width 1
    else if constexpr (SEG == 1) return 64 + 4*m;  // width 3 padded to 4
    else return 320 + 8*m;                         // width 5 padded to 8
}
template<int L>
__device__ __forceinline__ void load_xvec(const u16* p, float* o) {
    if constexpr (L == 0) {
        o[0] = bf2f(p[0]);
    } else if constexpr (L == 1) {
        uint2 r = *reinterpret_cast<const uint2*>(p);
        o[0] = bf2f((u16)(r.x & 0xffff)); o[1] = bf2f((u16)(r.x >> 16)); o[2] = bf2f((u16)(r.y & 0xffff));
    } else {
        uint4 r = *reinterpret_cast<const uint4*>(p);
        o[0] = bf2f((u16)(r.x & 0xffff)); o[1] = bf2f((u16)(r.x >> 16));
        o[2] = bf2f((u16)(r.y & 0xffff)); o[3] = bf2f((u16)(r.y >> 16));
        o[4] = bf2f((u16)(r.z & 0xffff));
    }
}

// ---------------- LDS staging: one chunk = 4 u = 2048 16B-units = 32 KiB ------------
// Wt workspace layout: chunk g = pid*16 + c, 16384 u16 each, already swizzled so that
// linear (lane-ordered) global_load_lds + swizzled ds_read give conflict-free access.
__device__ __forceinline__ void stage_chunk(const u16* __restrict__ Wtb, int g,
                                            u16* lbuf, int tid) {
    const u16* src = Wtb + ((size_t)g << 14);
    #pragma unroll
    for (int qq = 0; qq < 8; ++qq) {
        const int off = qq*2048 + tid*8;       // u16 units; 16B per thread, lane-linear
        __builtin_amdgcn_global_load_lds(
            (const __attribute__((address_space(1))) void*)(const void*)(src + off),
            (__attribute__((address_space(3))) void*)(void*)(lbuf + off),
            16, 0, 0);
    }
}

// ---------------- compute 4 u's (one chunk) from LDS ---------------------------------
template<int PID, int SEG1, int SEG2, int KOUT>
__device__ __forceinline__ void compute_chunk(const u16* __restrict__ lbuf,
                                              const u16* __restrict__ x1r,
                                              const float (&b2)[16][2*SEG2+1],
                                              int c, f32x4* acc, int lane) {
    const int kb = lane >> 4, nl = lane & 15;
    #pragma unroll
    for (int uu = 0; uu < 4; ++uu) {
        float a1[2*SEG1+1];
        load_xvec<SEG1>(x1r + soff<SEG1>(c*4 + uu), a1);
        float pre[CGT<PID>::n];
        #pragma unroll
        for (int t = 0; t < CGT<PID>::n; ++t)
            pre[t] = (CGT<PID>::e[t].k == KOUT) ? CGT<PID>::e[t].c * a1[CGT<PID>::e[t].i] : 0.0f;
        #pragma unroll
        for (int h = 0; h < 2; ++h) {
            bf16x8 af;
            #pragma unroll
            for (int e = 0; e < 8; ++e) {
                float s = 0.0f;
                #pragma unroll
                for (int t = 0; t < CGT<PID>::n; ++t)
                    if (CGT<PID>::e[t].k == KOUT)
                        s += pre[t] * b2[h*8 + e][CGT<PID>::e[t].j];
                af[e] = (short)f2bf(s);
            }
            const int m = uu*8 + h*4 + kb;
            #pragma unroll
            for (int nf = 0; nf < 4; ++nf) {
                const int w  = nf*16 + nl;
                const int s_ = w*32 + (m ^ (w & 31));   // XOR swizzle (matches prep_w)
                bf16x8 bfrag = *reinterpret_cast<const bf16x8*>(lbuf + s_*8);
                acc[nf] = __builtin_amdgcn_mfma_f32_16x16x32_bf16(af, bfrag, acc[nf], 0, 0, 0);
            }
        }
    }
}

// ---------------- one path: 16 chunks, double-buffered staging ----------------------
template<int PID, int SEG1, int SEG2, int KOUT>
__device__ __forceinline__ void run_path_lds(const u16* __restrict__ x1r, const u16* __restrict__ x2r,
                                             const u16* __restrict__ Wtb, u16* lds,
                                             f32x4* acc, int lane, int tid,
                                             int& q, int nchunks, int gbase) {
    constexpr int D2 = 2*SEG2 + 1;
    const int kb = lane >> 4;
    float b2[16][D2];
    #pragma unroll
    for (int h = 0; h < 2; ++h)
        #pragma unroll
        for (int e = 0; e < 8; ++e)
            load_xvec<SEG2>(x2r + soff<SEG2>(h*32 + kb*8 + e), b2[h*8 + e]);

    for (int c = 0; c < 16; ++c) {
        __syncthreads();                          // drains staging of chunk q (vmcnt)
        if (q + 1 < nchunks)
            stage_chunk(Wtb, gbase + q + 1, lds + (((q + 1) & 1) << 14), tid);
        compute_chunk<PID,SEG1,SEG2,KOUT>(lds + ((q & 1) << 14), x1r, b2, c, acc, lane);
        ++q;
    }
}

// ---------------- one unit = (io, kout) ----------------------------------------------
template<int IO, int KOUT>
__device__ __forceinline__ void run_unit(const u16* __restrict__ XB1, const u16* __restrict__ XB2,
                                         const u16* __restrict__ Wtb, float* __restrict__ out,
                                         int ztile, u16* lds) {
    constexpr int NP = (IO == 0) ? 3 : 4;
    constexpr int GB = (IO == 0) ? 0 : (IO == 1 ? 48 : 112);   // first pid * 16
    const int tid = threadIdx.x;
    const int lane = tid & 63, wave = tid >> 6;
    const int zin = ztile*64 + wave*16 + (lane & 15);
    const u16* x1r = XB1 + (size_t)zin*ROWE;
    const u16* x2r = XB2 + (size_t)zin*ROWE;
    f32x4 acc[4];
    #pragma unroll
    for (int nf = 0; nf < 4; ++nf) acc[nf] = (f32x4){0.f, 0.f, 0.f, 0.f};

    int q = 0;
    stage_chunk(Wtb, GB, lds, tid);               // prologue: chunk 0 -> buf 0

    if constexpr (IO == 0) {
        run_path_lds<0,0,0,KOUT>(x1r, x2r, Wtb, lds, acc, lane, tid, q, NP*16, GB);
        run_path_lds<1,1,1,KOUT>(x1r, x2r, Wtb, lds, acc, lane, tid, q, NP*16, GB);
        run_path_lds<2,2,2,KOUT>(x1r, x2r, Wtb, lds, acc, lane, tid, q, NP*16, GB);
    } else if constexpr (IO == 1) {
        run_path_lds<3,0,1,KOUT>(x1r, x2r, Wtb, lds, acc, lane, tid, q, NP*16, GB);
        run_path_lds<4,1,0,KOUT>(x1r, x2r, Wtb, lds, acc, lane, tid, q, NP*16, GB);
        run_path_lds<5,1,2,KOUT>(x1r, x2r, Wtb, lds, acc, lane, tid, q, NP*16, GB);
        run_path_lds<6,2,1,KOUT>(x1r, x2r, Wtb, lds, acc, lane, tid, q, NP*16, GB);
    } else {
        run_path_lds<7,0,2,KOUT>(x1r, x2r, Wtb, lds, acc, lane, tid, q, NP*16, GB);
        run_path_lds<8,1,1,KOUT>(x1r, x2r, Wtb, lds, acc, lane, tid, q, NP*16, GB);
        run_path_lds<9,2,0,KOUT>(x1r, x2r, Wtb, lds, acc, lane, tid, q, NP*16, GB);
        run_path_lds<10,2,2,KOUT>(x1r, x2r, Wtb, lds, acc, lane, tid, q, NP*16, GB);
    }

    // epilogue: C/D layout col=lane&15 (w), row=(lane>>4)*4+reg (z)
    constexpr int KO   = 2*IO + 1;
    constexpr int OFFI = (IO == 0) ? 0 : (IO == 1 ? 64 : 256);
    const int zoutb = ztile*64 + wave*16 + (lane >> 4)*4;
    const int nl = lane & 15;
    #pragma unroll
    for (int nf = 0; nf < 4; ++nf) {
        const int wcol = nf*16 + nl;
        #pragma unroll
        for (int r = 0; r < 4; ++r)
            out[(size_t)(zoutb + r)*576 + OFFI + wcol*KO + KOUT] = acc[nf][r] * 0.041666666666666664f;
    }
}

__global__ __launch_bounds__(256) void tp_main(const u16* __restrict__ XB1, const u16* __restrict__ XB2,
                                               const u16* __restrict__ Wtb, float* __restrict__ out) {
    __shared__ u16 smem[2*16384];                 // 64 KiB, double-buffered 32 KiB chunks
    const int unit  = blockIdx.x % 9;
    const int ztile = blockIdx.x / 9;
    switch (unit) {
        case 0: run_unit<0,0>(XB1, XB2, Wtb, out, ztile, smem); break;
        case 1: run_unit<1,0>(XB1, XB2, Wtb, out, ztile, smem); break;
        case 2: run_unit<1,1>(XB1, XB2, Wtb, out, ztile, smem); break;
        case 3: run_unit<1,2>(XB1, XB2, Wtb, out, ztile, smem); break;
        case 4: run_unit<2,0>(XB1, XB2, Wtb, out, ztile, smem); break;
        case 5: run_unit<2,1>(XB1, XB2, Wtb, out, ztile, smem); break;
        case 6: run_unit<2,2>(XB1, XB2, Wtb, out, ztile, smem); break;
        case 7: run_unit<2,3>(XB1, XB2, Wtb, out, ztile, smem); break;
        default: run_unit<2,4>(XB1, XB2, Wtb, out, ztile, smem); break;
    }
}

// ---------------- prep kernels ----------------
// x -> padded bf16 rows [z][ROWE]
__global__ void prep_x(const float* __restrict__ x1, const float* __restrict__ x2,
                       u16* __restrict__ XB1, u16* __restrict__ XB2) {
    int g = blockIdx.x * 256 + threadIdx.x;
    const int PER = NZ * 192;
    if (g >= 2*PER) return;
    const float* src; u16* dst;
    if (g < PER) { src = x1; dst = XB1; } else { src = x2; dst = XB2; g -= PER; }
    const int zz = g / 192, s = g - zz*192, seg = s >> 6, m = s & 63;
    const float* sp = src + zz*576;
    u16* dp = dst + zz*ROWE;
    if (seg == 0) {
        dp[m] = f2bf(sp[m]);
    } else if (seg == 1) {
        u16 t0 = f2bf(sp[64 + m*3 + 0]);
        u16 t1 = f2bf(sp[64 + m*3 + 1]);
        u16 t2 = f2bf(sp[64 + m*3 + 2]);
        uint2 pk; pk.x = (unsigned)t0 | ((unsigned)t1 << 16); pk.y = (unsigned)t2;
        *reinterpret_cast<uint2*>(dp + 64 + m*4) = pk;
    } else {
        u16 t[5];
        #pragma unroll
        for (int c = 0; c < 5; ++c) t[c] = f2bf(sp[256 + m*5 + c]);
        uint4 pk;
        pk.x = (unsigned)t[0] | ((unsigned)t[1] << 16);
        pk.y = (unsigned)t[2] | ((unsigned)t[3] << 16);
        pk.z = (unsigned)t[4];
        pk.w = 0u;
        *reinterpret_cast<uint4*>(dp + 320 + m*8) = pk;
    }
}

// W[p][u][v][w] f32 -> swizzled bf16 chunks: chunk g=p*16+c holds u=c*4+uu,
// 16B unit (w, m=uu*8+h*4+kb) at physical slot s = w*32 + (m ^ (w&31)),
// containing W[p][u][h*32+kb*8+e][w] for e=0..7.
__global__ void prep_w(const float* __restrict__ W, u16* __restrict__ Wtb) {
    __shared__ float ld[4096];
    const int b = blockIdx.x;            // 0..703 : (p,u)
    const int p = b >> 6, u = b & 63;
    const int tid = threadIdx.x;
    const float* src = W + ((size_t)(p*64 + u) << 12);
    #pragma unroll
    for (int i = 0; i < 16; ++i) ld[tid + i*256] = src[tid + i*256];   // coalesced
    __syncthreads();
    const int c = u >> 2, uu = u & 3;
    #pragma unroll
    for (int r = 0; r < 2; ++r) {
        const int j = r*256 + tid;       // 512 16B-units for this (p,u)
        const int w = j & 63, ms = j >> 6;         // ms = h*4+kb in [0,8)
        const int m = uu*8 + ms;
        const int h = ms >> 2, kb = ms & 3;
        const int vb = h*32 + kb*8;
        u16 tmp[8];
        #pragma unroll
        for (int e = 0; e < 8; ++e) tmp[e] = f2bf(ld[(vb + e)*64 + w]);
        const int s_ = w*32 + (m ^ (w & 31));
        uint4 pk;
        pk.x = (unsigned)tmp[0] | ((unsigned)tmp[1] << 16);
        pk.y = (unsigned)tmp[2] | ((unsigned)tmp[3] << 16);
        pk.z = (unsigned)tmp[4] | ((unsigned)tmp[5] << 16);
        pk.w = (unsigned)tmp[6] | ((unsigned)tmp[7] << 16);
        *reinterpret_cast<uint4*>(Wtb + ((((size_t)(p*16 + c)) << 11) + s_)*8) = pk;
    }
}

extern "C" void kernel_launch(void* const* d_in, const int* in_sizes, int n_in,
                              void* d_out, int out_size, void* d_ws, size_t ws_size,
                              hipStream_t stream) {
    const float* x1 = (const float*)d_in[0];
    const float* x2 = (const float*)d_in[1];
    const float* W  = (const float*)d_in[2];
    float* out = (float*)d_out;

    u16* XB1 = (u16*)d_ws;                 // 4096*832*2  = 6.8 MB
    u16* XB2 = XB1 + NZ*ROWE;              // 6.8 MB
    u16* Wtb = XB2 + NZ*ROWE;              // 11*16*2048*8*2 = 5.8 MB
    if (ws_size < (size_t)(2*NZ*ROWE + 11*16*2048*8) * sizeof(u16)) return;

    hipLaunchKernelGGL(prep_x, dim3((2*NZ*192 + 255)/256), dim3(256), 0, stream, x1, x2, XB1, XB2);
    hipLaunchKernelGGL(prep_w, dim3(11*64), dim3(256), 0, stream, W, Wtb);
    hipLaunchKernelGGL(tp_main, dim3(64*9), dim3(256), 0, stream, XB1, XB2, Wtb, out);
}

// Round 4
// 274.266 us; speedup vs baseline: 3.0268x; 1.1304x over previous
//
#include <hip/hip_runtime.h>

// FullyConnectedTensorProduct: irreps 64x(0e+1o+2e) x same -> same, N=4096.
// out[z, OFF[io] + w*(2lo+1) + k] = (1/24) * sum_p sum_{u,v,i,j} W[p][u][v][w]*CG_p[i,j,k]*x1[z,u,i]*x2[z,v,j]
//
// R4 = R3 architecture (kout-merged units, u split across 4 waves, pre-swizzled W chunks,
// double-buffered global_load_lds staging) with ONE revert for bisect: A-fragment pack
// uses the R2-proven scalar f2bf instead of v_cvt_pk_bf16_f32 inline asm.

typedef unsigned short u16;
typedef __attribute__((ext_vector_type(8))) short bf16x8;   // 8 bf16 in 4 VGPRs
typedef __attribute__((ext_vector_type(4))) float f32x4;

#define NZ 4096
#define ROWE 832   // padded bf16 elems per z-row: seg0 64*1 + seg1 64*4 + seg2 64*8

__device__ __forceinline__ u16 f2bf(float x) {               // RNE f32->bf16
    unsigned u = __float_as_uint(x);
    return (u16)((u + 0x7FFFu + ((u >> 16) & 1u)) >> 16);
}
__device__ __forceinline__ float bf2f(u16 b) {
    return __uint_as_float(((unsigned)b) << 16);
}

// ---------------- Clebsch-Gordan tables (real basis, reference phase conventions) ----
struct CGE { int i, j, k; float c; };
template<int P> struct CGT;
template<> struct CGT<0> { static constexpr int n=1; static constexpr CGE e[1]={{0,0,0,1.0f}}; };
template<> struct CGT<1> { static constexpr int n=3; static constexpr CGE e[3]={
    {0,0,0,0.5773502691896258f},{1,1,0,0.5773502691896258f},{2,2,0,0.5773502691896258f}}; };
template<> struct CGT<2> { static constexpr int n=5; static constexpr CGE e[5]={
    {0,0,0,0.4472135954999579f},{1,1,0,0.4472135954999579f},{2,2,0,0.4472135954999579f},
    {3,3,0,0.4472135954999579f},{4,4,0,0.4472135954999579f}}; };
template<> struct CGT<3> { static constexpr int n=3; static constexpr CGE e[3]={
    {0,0,0,1.0f},{0,1,1,1.0f},{0,2,2,1.0f}}; };
template<> struct CGT<4> { static constexpr int n=3; static constexpr CGE e[3]={
    {0,0,0,1.0f},{1,0,1,1.0f},{2,0,2,1.0f}}; };
template<> struct CGT<5> { static constexpr int n=11; static constexpr CGE e[11]={
    {0,2,0,-0.31622776601683794f},{1,1,0,0.5477225575051661f},{0,4,0,-0.5477225575051661f},{2,0,0,0.5477225575051661f},
    {0,1,1,0.5477225575051661f},{2,3,1,0.5477225575051661f},{1,2,1,0.6324555320336759f},
    {2,2,2,-0.31622776601683794f},{1,3,2,0.5477225575051661f},{0,0,2,0.5477225575051661f},{2,4,2,0.5477225575051661f}}; };
template<> struct CGT<6> { static constexpr int n=11; static constexpr CGE e[11]={
    {2,0,0,-0.31622776601683794f},{1,1,0,0.5477225575051661f},{4,0,0,-0.5477225575051661f},{0,2,0,0.5477225575051661f},
    {1,0,1,0.5477225575051661f},{3,2,1,0.5477225575051661f},{2,1,1,0.6324555320336759f},
    {2,2,2,-0.31622776601683794f},{3,1,2,0.5477225575051661f},{0,0,2,0.5477225575051661f},{4,2,2,0.5477225575051661f}}; };
template<> struct CGT<7> { static constexpr int n=5; static constexpr CGE e[5]={
    {0,0,0,1.0f},{0,1,1,1.0f},{0,2,2,1.0f},{0,3,3,1.0f},{0,4,4,1.0f}}; };
template<> struct CGT<8> { static constexpr int n=11; static constexpr CGE e[11]={
    {0,2,0,0.7071067811865476f},{2,0,0,0.7071067811865476f},
    {0,1,1,0.7071067811865476f},{1,0,1,0.7071067811865476f},
    {0,0,2,-0.4082482904638630f},{1,1,2,0.8164965809277260f},{2,2,2,-0.4082482904638630f},
    {1,2,3,0.7071067811865476f},{2,1,3,0.7071067811865476f},
    {0,0,4,-0.7071067811865476f},{2,2,4,0.7071067811865476f}}; };
template<> struct CGT<9> { static constexpr int n=5; static constexpr CGE e[5]={
    {0,0,0,1.0f},{1,0,1,1.0f},{2,0,2,1.0f},{3,0,3,1.0f},{4,0,4,1.0f}}; };
template<> struct CGT<10> { static constexpr int n=25; static constexpr CGE e[25]={
    {0,2,0,-0.5345224838248488f},{2,0,0,-0.5345224838248488f},{1,3,0,0.4629100498862757f},{3,1,0,0.4629100498862757f},
    {0,3,1,0.4629100498862757f},{3,0,1,0.4629100498862757f},{1,4,1,-0.4629100498862757f},{4,1,1,-0.4629100498862757f},
    {1,2,1,0.2672612419124244f},{2,1,1,0.2672612419124244f},
    {0,0,2,-0.5345224838248488f},{1,1,2,0.2672612419124244f},{2,2,2,0.5345224838248488f},{3,3,2,0.2672612419124244f},{4,4,2,-0.5345224838248488f},
    {0,1,3,0.4629100498862757f},{1,0,3,0.4629100498862757f},{3,4,3,0.4629100498862757f},{4,3,3,0.4629100498862757f},
    {2,3,3,0.2672612419124244f},{3,2,3,0.2672612419124244f},
    {1,1,4,-0.4629100498862757f},{3,3,4,0.4629100498862757f},{2,4,4,-0.5345224838248488f},{4,2,4,-0.5345224838248488f}}; };

// ---------------- padded x layout helpers ----------------
template<int SEG>
__device__ __forceinline__ int soff(int m) {
    if constexpr (SEG == 0) return m;              // width 1
    else if constexpr (SEG == 1) return 64 + 4*m;  // width 3 padded to 4
    else return 320 + 8*m;                         // width 5 padded to 8
}
template<int L>
__device__ __forceinline__ void load_xvec(const u16* p, float* o) {
    if constexpr (L == 0) {
        o[0] = bf2f(p[0]);
    } else if constexpr (L == 1) {
        uint2 r = *reinterpret_cast<const uint2*>(p);
        o[0] = bf2f((u16)(r.x & 0xffff)); o[1] = bf2f((u16)(r.x >> 16)); o[2] = bf2f((u16)(r.y & 0xffff));
    } else {
        uint4 r = *reinterpret_cast<const uint4*>(p);
        o[0] = bf2f((u16)(r.x & 0xffff)); o[1] = bf2f((u16)(r.x >> 16));
        o[2] = bf2f((u16)(r.y & 0xffff)); o[3] = bf2f((u16)(r.y >> 16));
        o[4] = bf2f((u16)(r.z & 0xffff));
    }
}

// ---------------- LDS staging: one chunk = 32 KiB = {1 u per wave-quarter} ----------
// Wt layout: chunk g = pid*16 + c holds u in {q*16+c, q=0..3}; sub-chunk q is 8 KiB.
// 16B unit (w, ms=h*4+kb) at slot q*512 + w*8 + (ms ^ (w&7)); conflict-free on read.
__device__ __forceinline__ void stage_chunk(const u16* __restrict__ Wtb, int g,
                                            u16* lbuf, int tid) {
    const u16* src = Wtb + ((size_t)g << 14);
    #pragma unroll
    for (int qq = 0; qq < 8; ++qq) {
        const int off = qq*2048 + tid*8;       // 16B per thread, lane-linear
        __builtin_amdgcn_global_load_lds(
            (const __attribute__((address_space(1))) void*)(const void*)(src + off),
            (__attribute__((address_space(3))) void*)(void*)(lbuf + off),
            16, 0, 0);
    }
}

// ---------------- one u (one chunk) from LDS: KO kouts share the B-fragments --------
template<int PID, int S1, int S2, int KO>
__device__ __forceinline__ void chunk_compute(const u16* __restrict__ lbuf,
                                              const float (&a1)[2*S1+1],
                                              const float (&b2)[16][2*S2+1],
                                              f32x4 (&acc)[KO][4], int lane, int uq) {
    const int kb = lane >> 4, nl = lane & 15;
    float pre[CGT<PID>::n];
    #pragma unroll
    for (int t = 0; t < CGT<PID>::n; ++t)
        pre[t] = CGT<PID>::e[t].c * a1[CGT<PID>::e[t].i];
    #pragma unroll
    for (int h = 0; h < 2; ++h) {
        bf16x8 bf[4];
        #pragma unroll
        for (int nf = 0; nf < 4; ++nf) {
            const int w = nf*16 + nl;
            const int slot = uq*512 + w*8 + ((h*4 + kb) ^ (w & 7));
            bf[nf] = *reinterpret_cast<const bf16x8*>(lbuf + slot*8);
        }
        #pragma unroll
        for (int ko = 0; ko < KO; ++ko) {
            bf16x8 af;                                  // R2-proven scalar pack (bisect)
            #pragma unroll
            for (int e = 0; e < 8; ++e) {
                float v = 0.f;
                #pragma unroll
                for (int t = 0; t < CGT<PID>::n; ++t)
                    if (CGT<PID>::e[t].k == ko)
                        v += pre[t] * b2[h*8 + e][CGT<PID>::e[t].j];
                af[e] = (short)f2bf(v);
            }
            #pragma unroll
            for (int nf = 0; nf < 4; ++nf)
                acc[ko][nf] = __builtin_amdgcn_mfma_f32_16x16x32_bf16(af, bf[nf], acc[ko][nf], 0, 0, 0);
        }
    }
}

// ---------------- one path: 16 chunks (u = uq*16 + c), double-buffered staging ------
template<int PID, int S1, int S2, int KO>
__device__ __forceinline__ void run_path_m(const u16* __restrict__ x1r, const u16* __restrict__ x2r,
                                           const u16* __restrict__ Wtb, u16* lds,
                                           f32x4 (&acc)[KO][4], int lane, int tid, int uq,
                                           int& q, int nchunks, int gbase) {
    constexpr int D1 = 2*S1 + 1, D2 = 2*S2 + 1;
    const int kb = lane >> 4;
    float b2[16][D2];
    #pragma unroll
    for (int h = 0; h < 2; ++h)
        #pragma unroll
        for (int e = 0; e < 8; ++e)
            load_xvec<S2>(x2r + soff<S2>(h*32 + kb*8 + e), b2[h*8 + e]);

    float a1[D1], a1n[D1];
    load_xvec<S1>(x1r + soff<S1>(uq*16), a1);
    for (int c = 0; c < 16; ++c) {
        __syncthreads();                          // chunk q staged; all readers past q^1
        if (q + 1 < nchunks)
            stage_chunk(Wtb, gbase + q + 1, lds + (((q + 1) & 1) << 14), tid);
        load_xvec<S1>(x1r + soff<S1>(uq*16 + ((c + 1) & 15)), a1n);   // prefetch next u
        chunk_compute<PID,S1,S2,KO>(lds + ((q & 1) << 14), a1, b2, acc, lane, uq);
        #pragma unroll
        for (int d = 0; d < D1; ++d) a1[d] = a1n[d];
        ++q;
    }
}

// ---------------- one unit = (ztile16, io): all kouts, u split across 4 waves -------
template<int IO>
__device__ __forceinline__ void run_unit(const u16* __restrict__ XB1, const u16* __restrict__ XB2,
                                         const u16* __restrict__ Wtb, float* __restrict__ out,
                                         int zt, u16* lds) {
    constexpr int KO = 2*IO + 1;
    constexpr int NP = (IO == 0) ? 3 : 4;
    constexpr int GB = (IO == 0) ? 0 : (IO == 1 ? 48 : 112);   // first pid * 16
    constexpr int OFFI = (IO == 0) ? 0 : (IO == 1 ? 64 : 256);
    const int tid = threadIdx.x;
    const int lane = tid & 63, uq = tid >> 6;     // wave = u-quarter
    const int zin = zt*16 + (lane & 15);
    const u16* x1r = XB1 + (size_t)zin*ROWE;
    const u16* x2r = XB2 + (size_t)zin*ROWE;
    f32x4 acc[KO][4];
    #pragma unroll
    for (int k = 0; k < KO; ++k)
        #pragma unroll
        for (int nf = 0; nf < 4; ++nf) acc[k][nf] = (f32x4){0.f, 0.f, 0.f, 0.f};

    int q = 0;
    stage_chunk(Wtb, GB, lds, tid);               // prologue: chunk 0 -> buf 0

    if constexpr (IO == 0) {
        run_path_m<0,0,0,KO>(x1r, x2r, Wtb, lds, acc, lane, tid, uq, q, NP*16, GB);
        run_path_m<1,1,1,KO>(x1r, x2r, Wtb, lds, acc, lane, tid, uq, q, NP*16, GB);
        run_path_m<2,2,2,KO>(x1r, x2r, Wtb, lds, acc, lane, tid, uq, q, NP*16, GB);
    } else if constexpr (IO == 1) {
        run_path_m<3,0,1,KO>(x1r, x2r, Wtb, lds, acc, lane, tid, uq, q, NP*16, GB);
        run_path_m<4,1,0,KO>(x1r, x2r, Wtb, lds, acc, lane, tid, uq, q, NP*16, GB);
        run_path_m<5,1,2,KO>(x1r, x2r, Wtb, lds, acc, lane, tid, uq, q, NP*16, GB);
        run_path_m<6,2,1,KO>(x1r, x2r, Wtb, lds, acc, lane, tid, uq, q, NP*16, GB);
    } else {
        run_path_m<7,0,2,KO>(x1r, x2r, Wtb, lds, acc, lane, tid, uq, q, NP*16, GB);
        run_path_m<8,1,1,KO>(x1r, x2r, Wtb, lds, acc, lane, tid, uq, q, NP*16, GB);
        run_path_m<9,2,0,KO>(x1r, x2r, Wtb, lds, acc, lane, tid, uq, q, NP*16, GB);
        run_path_m<10,2,2,KO>(x1r, x2r, Wtb, lds, acc, lane, tid, uq, q, NP*16, GB);
    }

    // ---- cross-wave (u-quarter) reduction via LDS, then store (wave 0) ----
    __syncthreads();
    float* red = reinterpret_cast<float*>(lds);   // reuse staging buffers (<= 61.4 KB)
    if (uq > 0) {
        const int base = ((uq - 1)*64 + lane) * (KO*16);
        #pragma unroll
        for (int k = 0; k < KO; ++k)
            #pragma unroll
            for (int nf = 0; nf < 4; ++nf)
                #pragma unroll
                for (int r = 0; r < 4; ++r)
                    red[base + (k*4 + nf)*4 + r] = acc[k][nf][r];
    }
    __syncthreads();
    if (uq == 0) {
        const int nl = lane & 15;
        const int zoutb = zt*16 + (lane >> 4)*4;
        #pragma unroll
        for (int k = 0; k < KO; ++k)
            #pragma unroll
            for (int nf = 0; nf < 4; ++nf) {
                f32x4 s = acc[k][nf];
                #pragma unroll
                for (int wv = 1; wv < 4; ++wv) {
                    const int base = ((wv - 1)*64 + lane) * (KO*16) + (k*4 + nf)*4;
                    #pragma unroll
                    for (int r = 0; r < 4; ++r) s[r] += red[base + r];
                }
                const int wcol = nf*16 + nl;
                #pragma unroll
                for (int r = 0; r < 4; ++r)
                    out[(size_t)(zoutb + r)*576 + OFFI + wcol*KO + k] = s[r] * 0.041666666666666664f;
            }
    }
}

__global__ __launch_bounds__(256) void tp_main(const u16* __restrict__ XB1, const u16* __restrict__ XB2,
                                               const u16* __restrict__ Wtb, float* __restrict__ out) {
    __shared__ u16 smem[2*16384];                 // 64 KiB: dbuf staging / reduce scratch
    const int io = blockIdx.x % 3;
    const int zt = blockIdx.x / 3;
    if (io == 0)      run_unit<0>(XB1, XB2, Wtb, out, zt, smem);
    else if (io == 1) run_unit<1>(XB1, XB2, Wtb, out, zt, smem);
    else              run_unit<2>(XB1, XB2, Wtb, out, zt, smem);
}

// ---------------- prep kernels ----------------
// x -> padded bf16 rows [z][ROWE]
__global__ void prep_x(const float* __restrict__ x1, const float* __restrict__ x2,
                       u16* __restrict__ XB1, u16* __restrict__ XB2) {
    int g = blockIdx.x * 256 + threadIdx.x;
    const int PER = NZ * 192;
    if (g >= 2*PER) return;
    const float* src; u16* dst;
    if (g < PER) { src = x1; dst = XB1; } else { src = x2; dst = XB2; g -= PER; }
    const int zz = g / 192, s = g - zz*192, seg = s >> 6, m = s & 63;
    const float* sp = src + zz*576;
    u16* dp = dst + zz*ROWE;
    if (seg == 0) {
        dp[m] = f2bf(sp[m]);
    } else if (seg == 1) {
        u16 t0 = f2bf(sp[64 + m*3 + 0]);
        u16 t1 = f2bf(sp[64 + m*3 + 1]);
        u16 t2 = f2bf(sp[64 + m*3 + 2]);
        uint2 pk; pk.x = (unsigned)t0 | ((unsigned)t1 << 16); pk.y = (unsigned)t2;
        *reinterpret_cast<uint2*>(dp + 64 + m*4) = pk;
    } else {
        u16 t[5];
        #pragma unroll
        for (int c = 0; c < 5; ++c) t[c] = f2bf(sp[256 + m*5 + c]);
        uint4 pk;
        pk.x = (unsigned)t[0] | ((unsigned)t[1] << 16);
        pk.y = (unsigned)t[2] | ((unsigned)t[3] << 16);
        pk.z = (unsigned)t[4];
        pk.w = 0u;
        *reinterpret_cast<uint4*>(dp + 320 + m*8) = pk;
    }
}

// W[p][u][v][w] f32 -> chunked/swizzled bf16:
// chunk g = p*16 + (u&15); sub-chunk q = u>>4 (512 16B-units);
// unit (w, ms=h*4+kb) at slot q*512 + w*8 + (ms ^ (w&7)), holding W[p][u][h*32+kb*8+e][w].
__global__ void prep_w(const float* __restrict__ W, u16* __restrict__ Wtb) {
    __shared__ float ld[4096];
    const int b = blockIdx.x;            // 0..703 : (p,u)
    const int p = b >> 6, u = b & 63;
    const int tid = threadIdx.x;
    const float* src = W + ((size_t)(p*64 + u) << 12);
    #pragma unroll
    for (int i = 0; i < 16; ++i) ld[tid + i*256] = src[tid + i*256];   // coalesced
    __syncthreads();
    const int g  = p*16 + (u & 15);
    const int q_ = u >> 4;
    #pragma unroll
    for (int r = 0; r < 2; ++r) {
        const int j = r*256 + tid;                 // 512 16B-units for this (p,u)
        const int w = j & 63, ms = j >> 6;         // ms = h*4+kb in [0,8)
        const int h = ms >> 2, kb = ms & 3;
        const int vb = h*32 + kb*8;
        u16 tmp[8];
        #pragma unroll
        for (int e = 0; e < 8; ++e) tmp[e] = f2bf(ld[(vb + e)*64 + w]);
        const int unit = q_*512 + w*8 + (ms ^ (w & 7));
        uint4 pk;
        pk.x = (unsigned)tmp[0] | ((unsigned)tmp[1] << 16);
        pk.y = (unsigned)tmp[2] | ((unsigned)tmp[3] << 16);
        pk.z = (unsigned)tmp[4] | ((unsigned)tmp[5] << 16);
        pk.w = (unsigned)tmp[6] | ((unsigned)tmp[7] << 16);
        *reinterpret_cast<uint4*>(Wtb + (((size_t)g*2048 + unit))*8) = pk;
    }
}

extern "C" void kernel_launch(void* const* d_in, const int* in_sizes, int n_in,
                              void* d_out, int out_size, void* d_ws, size_t ws_size,
                              hipStream_t stream) {
    const float* x1 = (const float*)d_in[0];
    const float* x2 = (const float*)d_in[1];
    const float* W  = (const float*)d_in[2];
    float* out = (float*)d_out;

    u16* XB1 = (u16*)d_ws;                 // 4096*832*2  = 6.8 MB
    u16* XB2 = XB1 + NZ*ROWE;              // 6.8 MB
    u16* Wtb = XB2 + NZ*ROWE;              // 11*16*2048*8*2 = 5.8 MB
    if (ws_size < (size_t)(2*NZ*ROWE + 11*16*2048*8) * sizeof(u16)) return;

    hipLaunchKernelGGL(prep_x, dim3((2*NZ*192 + 255)/256), dim3(256), 0, stream, x1, x2, XB1, XB2);
    hipLaunchKernelGGL(prep_w, dim3(11*64), dim3(256), 0, stream, W, Wtb);
    hipLaunchKernelGGL(tp_main, dim3(256*3), dim3(256), 0, stream, XB1, XB2, Wtb, out);
}